// Round 1
// baseline (832.508 us; speedup 1.0000x reference)
//
#include <hip/hip_runtime.h>
#include <hip/hip_bf16.h>
#include <math.h>

#define N 256
#define D 768
#define H 384
#define BATCH 128

// ---------------- K1: row-normalize class & context features ----------------
__global__ void k_norm(const float* __restrict__ cf, const float* __restrict__ ctx,
                       float* __restrict__ vsn, float* __restrict__ csn) {
    int row = blockIdx.x;               // 0..511
    const float* src;
    float* dst;
    if (row < N) { src = cf  + row * D;      dst = vsn + row * D; }
    else         { src = ctx + (row - N) * D; dst = csn + (row - N) * D; }
    int t = threadIdx.x;                 // 256
    float s = 0.f;
    for (int d = t; d < D; d += 256) { float v = src[d]; s += v * v; }
    __shared__ float red[256];
    red[t] = s; __syncthreads();
    for (int off = 128; off > 0; off >>= 1) {
        if (t < off) red[t] += red[t + off];
        __syncthreads();
    }
    float inv = 1.0f / sqrtf(red[0]);
    for (int d = t; d < D; d += 256) dst[d] = src[d] * inv;
}

// ---------------- K2: a = class_features @ w1  (256x384, K=768) -------------
__global__ void k_a(const float* __restrict__ cf, const float* __restrict__ w1,
                    float* __restrict__ a) {
    __shared__ float rows[8 * 768];      // 24 KB
    int i0 = blockIdx.x * 8;
    int t = threadIdx.x;                 // 384
    for (int idx = t; idx < 8 * 768; idx += 384) rows[idx] = cf[i0 * 768 + idx];
    __syncthreads();
    float acc[8] = {0.f,0.f,0.f,0.f,0.f,0.f,0.f,0.f};
    for (int d = 0; d < 768; d++) {
        float w = w1[d * 384 + t];
        #pragma unroll
        for (int r = 0; r < 8; r++) acc[r] += rows[r * 768 + d] * w;
    }
    #pragma unroll
    for (int r = 0; r < 8; r++) a[(i0 + r) * 384 + t] = acc[r];
}

// ---------------- K3: vs = vsn@vsn^T, cs = csn@csn^T ------------------------
__global__ void k_gram(const float* __restrict__ vsn, const float* __restrict__ csn,
                       float* __restrict__ vs, float* __restrict__ cs) {
    bool second = blockIdx.x >= 64;
    const float* S = second ? csn : vsn;
    float* O       = second ? cs  : vs;
    int i0 = (second ? blockIdx.x - 64 : blockIdx.x) * 4;
    __shared__ float rows[4 * 768];      // 12 KB
    int t = threadIdx.x;                 // 256
    for (int idx = t; idx < 4 * 768; idx += 256) rows[idx] = S[i0 * 768 + idx];
    __syncthreads();
    float acc[4] = {0.f,0.f,0.f,0.f};
    const float* rj = S + t * 768;
    for (int d = 0; d < 768; d++) {
        float v = rj[d];
        #pragma unroll
        for (int r = 0; r < 4; r++) acc[r] += rows[r * 768 + d] * v;
    }
    #pragma unroll
    for (int r = 0; r < 4; r++) O[(i0 + r) * 256 + t] = acc[r];
}

// ---------------- K4: e1 = combined * sigmoid(relu(ai-aj+b1)@w2+b2) * ratio -
__global__ void k_e1(const float* __restrict__ a, const float* __restrict__ b1,
                     const float* __restrict__ w2, const float* __restrict__ b2,
                     const float* __restrict__ vs, const float* __restrict__ cs,
                     const int* __restrict__ ic, float* __restrict__ e1) {
    int i = blockIdx.x;
    __shared__ float ai[384], sb1[384], sw2[384];
    int t = threadIdx.x;                 // 256 (4 waves)
    for (int k = t; k < 384; k += 256) {
        ai[k] = a[i * 384 + k]; sb1[k] = b1[k]; sw2[k] = w2[k];
    }
    __syncthreads();
    float b2v = b2[0];
    float cnt_i = (float)ic[i];
    int wave = t >> 6, lane = t & 63;
    for (int j = wave; j < 256; j += 4) {
        float s = 0.f;
        for (int k = lane; k < 384; k += 64) {
            float h = ai[k] - a[j * 384 + k] + sb1[k];
            if (h > 0.f) s += h * sw2[k];
        }
        #pragma unroll
        for (int off = 32; off > 0; off >>= 1) s += __shfl_down(s, off, 64);
        if (lane == 0) {
            float sw = 1.0f / (1.0f + expf(-(s + b2v)));
            float comb = 0.7f * vs[i * 256 + j] + 0.3f * cs[i * 256 + j];
            float cj = (float)ic[j];
            float mn = fminf(cnt_i, cj), mx = fmaxf(cnt_i, cj);
            float ratio = mn / fmaxf(mx, 1.0f);
            e1[i * 256 + j] = comb * sw * ratio;
        }
    }
}

// ---------------- K5: shared_sum = M@M^T, shared_cnt = A@A^T ----------------
__global__ void k_shared(const int* __restrict__ co, const float* __restrict__ vs,
                         float* __restrict__ ss, float* __restrict__ sc) {
    int i0 = blockIdx.x * 4;
    __shared__ float Mi[4 * 256];
    __shared__ float Ai[4 * 256];
    int t = threadIdx.x;                 // 256
    for (int idx = t; idx < 4 * 256; idx += 256) {
        int c = co[i0 * 256 + idx];
        float aa = c > 50 ? 1.f : 0.f;
        Ai[idx] = aa; Mi[idx] = aa * vs[i0 * 256 + idx];
    }
    __syncthreads();
    float accS[4] = {0.f,0.f,0.f,0.f}, accC[4] = {0.f,0.f,0.f,0.f};
    const int* coj = co + t * 256;
    const float* vsj = vs + t * 256;
    for (int k = 0; k < 256; k++) {
        int c = coj[k];
        if (c > 50) {
            float vjk = vsj[k];
            #pragma unroll
            for (int r = 0; r < 4; r++) { accS[r] += Mi[r * 256 + k] * vjk; accC[r] += Ai[r * 256 + k]; }
        }
    }
    #pragma unroll
    for (int r = 0; r < 4; r++) { ss[(i0 + r) * 256 + t] = accS[r]; sc[(i0 + r) * 256 + t] = accC[r]; }
}

// ---------------- K6: top-5 of each co row (ties -> lower index first) ------
__global__ void k_topk(const int* __restrict__ co, float* __restrict__ topv,
                       int* __restrict__ topi) {
    int row = blockIdx.x * 64 + threadIdx.x;   // 4 blocks x 64
    const int* r = co + row * 256;
    int ch[5];
    for (int s = 0; s < 5; s++) {
        float bv = -1.f; int bi = 0;
        for (int k = 0; k < 256; k++) {
            bool used = false;
            #pragma unroll
            for (int u = 0; u < 5; u++) if (u < s) used |= (ch[u] == k);
            if (used) continue;
            float v = (float)r[k];
            if (v > bv) { bv = v; bi = k; }   // strict > keeps lowest index on ties
        }
        ch[s] = bi; topv[row * 5 + s] = bv; topi[row * 5 + s] = bi;
    }
}

// ---------------- K7: assemble E (tiered), zero diag, per-row max -----------
__global__ void k_assemble(const int* __restrict__ co, const float* __restrict__ vs,
                           const float* __restrict__ cs, const float* __restrict__ e1,
                           const float* __restrict__ ss, const float* __restrict__ sc,
                           const float* __restrict__ topv, const int* __restrict__ topi,
                           float* __restrict__ E, float* __restrict__ partials) {
    int i = blockIdx.x, j = threadIdx.x;
    int cij = co[i * 256 + j];
    float e;
    if (i == j) {
        e = 0.f;
    } else if (cij > 50) {                 // tier1
        e = e1[i * 256 + j];
    } else if (cij > 10) {                 // tier2
        float conf = (float)cij / 50.0f;
        float comb = 0.7f * vs[i * 256 + j] + 0.3f * cs[i * 256 + j];
        float cnt = sc[i * 256 + j];
        float avg = ss[i * 256 + j] / fmaxf(cnt, 1.f);
        e = (cnt > 0.f) ? conf * comb + (1.f - conf) * avg : conf * comb;
    } else {                               // tier3: transitive via top-5
        float tvi[5], tvj[5]; int tii[5], tij[5];
        #pragma unroll
        for (int k = 0; k < 5; k++) {
            tvi[k] = topv[i * 5 + k]; tii[k] = topi[i * 5 + k];
            tvj[k] = topv[j * 5 + k]; tij[k] = topi[j * 5 + k];
        }
        float trans = 0.f, tot = 0.f;
        #pragma unroll
        for (int k = 0; k < 5; k++) {
            if (!(tvi[k] > 10.f)) continue;
            float vin_i = vs[i * 256 + tii[k]];
            #pragma unroll
            for (int l = 0; l < 5; l++) {
                if (!(tvj[l] > 10.f)) continue;
                int cc = co[tii[k] * 256 + tij[l]];
                if (cc <= 0) continue;
                float w = tvi[k] * tvj[l] / 50.f;
                float sim = vin_i * vs[j * 256 + tij[l]] * vs[tii[k] * 256 + tij[l]];
                trans += w * sim; tot += w;
            }
        }
        e = (tot > 0.f) ? trans / tot : 0.1f * cs[i * 256 + j];
    }
    E[i * 256 + j] = e;
    __shared__ float red[256];
    red[j] = e; __syncthreads();
    for (int off = 128; off > 0; off >>= 1) {
        if (j < off) red[j] = fmaxf(red[j], red[j + off]);
        __syncthreads();
    }
    if (j == 0) partials[i] = red[0];
}

// ---------------- K8: global max -> scale = mx>0 ? 1/mx : 1 -----------------
__global__ void k_scale(const float* __restrict__ partials, float* __restrict__ scalep) {
    __shared__ float red[256];
    int t = threadIdx.x;
    red[t] = partials[t]; __syncthreads();
    for (int off = 128; off > 0; off >>= 1) {
        if (t < off) red[t] = fmaxf(red[t], red[t + off]);
        __syncthreads();
    }
    if (t == 0) { float mx = red[0]; scalep[0] = (mx > 0.f) ? 1.0f / mx : 1.0f; }
}

// ---------------- K9: out[b,i,d] = x[b,i,d] + s * sum_j E[i,j] x[b,j,d] -----
// 64x64 tile per block, BK=16, 256 threads (16x16), 4x4 micro-tile.
__global__ __launch_bounds__(256) void k_einsum(const float* __restrict__ E,
                                                const float* __restrict__ scalep,
                                                const float* __restrict__ x,
                                                float* __restrict__ out) {
    int d0 = blockIdx.x * 64, i0 = blockIdx.y * 64, b = blockIdx.z;
    float s = scalep[0];
    __shared__ __align__(16) float Es[16 * 64];   // [k][i]
    __shared__ __align__(16) float Xs[16 * 64];   // [k][d]
    int t = threadIdx.x;
    int tx = t & 15, ty = t >> 4;
    float acc[4][4] = {};
    const float* xb = x + (size_t)b * 256 * 768;
    for (int k0 = 0; k0 < 256; k0 += 16) {
        #pragma unroll
        for (int it = 0; it < 4; it++) {
            int ii = t & 63;
            int kk = (t >> 6) + it * 4;
            Es[kk * 64 + ii] = E[(i0 + ii) * 256 + k0 + kk] * s;
        }
        #pragma unroll
        for (int it = 0; it < 4; it++) {
            int idx = t + it * 256;
            int r = idx >> 6, c = idx & 63;
            Xs[r * 64 + c] = xb[(k0 + r) * 768 + d0 + c];
        }
        __syncthreads();
        #pragma unroll
        for (int kk = 0; kk < 16; kk++) {
            const float4 ev = *(const float4*)&Es[kk * 64 + ty * 4];
            const float4 xv = *(const float4*)&Xs[kk * 64 + tx * 4];
            float e[4]  = {ev.x, ev.y, ev.z, ev.w};
            float xr[4] = {xv.x, xv.y, xv.z, xv.w};
            #pragma unroll
            for (int r = 0; r < 4; r++)
                #pragma unroll
                for (int c2 = 0; c2 < 4; c2++) acc[r][c2] += e[r] * xr[c2];
        }
        __syncthreads();
    }
    #pragma unroll
    for (int r = 0; r < 4; r++) {
        int gi = i0 + ty * 4 + r;
        const float4 xres = *(const float4*)&xb[gi * 768 + d0 + tx * 4];
        float4 o;
        o.x = xres.x + acc[r][0]; o.y = xres.y + acc[r][1];
        o.z = xres.z + acc[r][2]; o.w = xres.w + acc[r][3];
        *(float4*)&out[((size_t)b * 256 + gi) * 768 + d0 + tx * 4] = o;
    }
}

extern "C" void kernel_launch(void* const* d_in, const int* in_sizes, int n_in,
                              void* d_out, int out_size, void* d_ws, size_t ws_size,
                              hipStream_t stream) {
    const float* x   = (const float*)d_in[0];
    const float* cf  = (const float*)d_in[1];
    const float* ctx = (const float*)d_in[2];
    const float* w1  = (const float*)d_in[3];
    const float* b1  = (const float*)d_in[4];
    const float* w2  = (const float*)d_in[5];
    const float* b2  = (const float*)d_in[6];
    const int*   co  = (const int*)d_in[7];
    const int*   ic  = (const int*)d_in[8];
    float* out = (float*)d_out;

    float* ws   = (float*)d_ws;
    float* vsn  = ws;                    // 196608
    float* csn  = vsn + 196608;          // 196608
    float* a    = csn + 196608;          // 98304
    float* vs   = a + 98304;             // 65536
    float* cs   = vs + 65536;            // 65536
    float* e1   = cs + 65536;            // 65536
    float* ss   = e1 + 65536;            // 65536
    float* sc   = ss + 65536;            // 65536
    float* E    = sc + 65536;            // 65536
    float* topv = E + 65536;             // 1280
    int*   topi = (int*)(topv + 1280);   // 1280
    float* partials = (float*)(topi + 1280); // 256
    float* scalep   = partials + 256;    // 1

    k_norm<<<512, 256, 0, stream>>>(cf, ctx, vsn, csn);
    k_a<<<32, 384, 0, stream>>>(cf, w1, a);
    k_gram<<<128, 256, 0, stream>>>(vsn, csn, vs, cs);
    k_e1<<<256, 256, 0, stream>>>(a, b1, w2, b2, vs, cs, ic, e1);
    k_shared<<<64, 256, 0, stream>>>(co, vs, ss, sc);
    k_topk<<<4, 64, 0, stream>>>(co, topv, topi);
    k_assemble<<<256, 256, 0, stream>>>(co, vs, cs, e1, ss, sc, topv, topi, E, partials);
    k_scale<<<1, 256, 0, stream>>>(partials, scalep);
    dim3 g(12, 4, BATCH);
    k_einsum<<<g, 256, 0, stream>>>(E, scalep, x, out);
}

// Round 2
// 463.924 us; speedup vs baseline: 1.7945x; 1.7945x over previous
//
#include <hip/hip_runtime.h>
#include <hip/hip_bf16.h>
#include <math.h>

#define N 256
#define D 768
#define BATCH 128

typedef float f32x4 __attribute__((ext_vector_type(4)));
typedef short bf16x8 __attribute__((ext_vector_type(8)));

// RNE fp32 -> bf16 (no NaN inputs in this problem)
static __device__ __forceinline__ unsigned short f2bf(float f) {
    unsigned int u = __float_as_uint(f);
    u += 0x7fffu + ((u >> 16) & 1u);
    return (unsigned short)(u >> 16);
}
static __device__ __forceinline__ unsigned int pack2bf(float lo, float hi) {
    unsigned int a = __float_as_uint(lo);
    unsigned int b = __float_as_uint(hi);
    a += 0x7fffu + ((a >> 16) & 1u);
    b += 0x7fffu + ((b >> 16) & 1u);
    return (a >> 16) | (b & 0xffff0000u);
}

// ---------------- K1: row-normalize class & context features ----------------
__global__ void k_norm(const float* __restrict__ cf, const float* __restrict__ ctx,
                       float* __restrict__ vsn, float* __restrict__ csn) {
    int row = blockIdx.x;               // 0..511
    const float* src;
    float* dst;
    if (row < N) { src = cf  + row * D;       dst = vsn + row * D; }
    else         { src = ctx + (row - N) * D; dst = csn + (row - N) * D; }
    int t = threadIdx.x;                 // 256
    float s = 0.f;
    for (int d = t; d < D; d += 256) { float v = src[d]; s += v * v; }
    __shared__ float red[256];
    red[t] = s; __syncthreads();
    for (int off = 128; off > 0; off >>= 1) {
        if (t < off) red[t] += red[t + off];
        __syncthreads();
    }
    float inv = 1.0f / sqrtf(red[0]);
    for (int d = t; d < D; d += 256) dst[d] = src[d] * inv;
}

// ---------------- K2: a = class_features @ w1  (256x384, K=768) -------------
__global__ void k_a(const float* __restrict__ cf, const float* __restrict__ w1,
                    float* __restrict__ a) {
    __shared__ float rows[8 * 768];      // 24 KB
    int i0 = blockIdx.x * 8;
    int t = threadIdx.x;                 // 384
    for (int idx = t; idx < 8 * 768; idx += 384) rows[idx] = cf[i0 * 768 + idx];
    __syncthreads();
    float acc[8] = {0.f,0.f,0.f,0.f,0.f,0.f,0.f,0.f};
    for (int d = 0; d < 768; d++) {
        float w = w1[d * 384 + t];
        #pragma unroll
        for (int r = 0; r < 8; r++) acc[r] += rows[r * 768 + d] * w;
    }
    #pragma unroll
    for (int r = 0; r < 8; r++) a[(i0 + r) * 384 + t] = acc[r];
}

// ---------------- K3: vs/cs gram, coalesced LDS-tiled (32x32 tiles) ---------
__global__ void k_gram2(const float* __restrict__ vsn, const float* __restrict__ csn,
                        float* __restrict__ vs, float* __restrict__ cs) {
    int bx = blockIdx.x;                 // 0..127
    const float* S = (bx >= 64) ? csn : vsn;
    float* O       = (bx >= 64) ? cs  : vs;
    int bi = bx & 63;
    int i0 = (bi >> 3) * 32, j0 = (bi & 7) * 32;
    __shared__ float Li[64][33], Lj[64][33];   // [k][row], padded
    int t = threadIdx.x;                 // 256
    int tx = t & 15, ty = t >> 4;
    float a00 = 0.f, a01 = 0.f, a10 = 0.f, a11 = 0.f;
    for (int k0 = 0; k0 < 768; k0 += 64) {
        #pragma unroll
        for (int s = 0; s < 8; s++) {
            int idx = s * 256 + t;
            int row = idx >> 6, kc = idx & 63;
            Li[kc][row] = S[(i0 + row) * 768 + k0 + kc];
            Lj[kc][row] = S[(j0 + row) * 768 + k0 + kc];
        }
        __syncthreads();
        #pragma unroll 4
        for (int kk = 0; kk < 64; kk++) {
            float iv0 = Li[kk][ty * 2], iv1 = Li[kk][ty * 2 + 1];
            float jv0 = Lj[kk][tx * 2], jv1 = Lj[kk][tx * 2 + 1];
            a00 += iv0 * jv0; a01 += iv0 * jv1;
            a10 += iv1 * jv0; a11 += iv1 * jv1;
        }
        __syncthreads();
    }
    O[(i0 + ty * 2)     * 256 + j0 + tx * 2]     = a00;
    O[(i0 + ty * 2)     * 256 + j0 + tx * 2 + 1] = a01;
    O[(i0 + ty * 2 + 1) * 256 + j0 + tx * 2]     = a10;
    O[(i0 + ty * 2 + 1) * 256 + j0 + tx * 2 + 1] = a11;
}

// ---------------- K4: e1 = combined * sigmoid(relu(ai-aj+b1)@w2+b2) * ratio -
__global__ void k_e1(const float* __restrict__ a, const float* __restrict__ b1,
                     const float* __restrict__ w2, const float* __restrict__ b2,
                     const float* __restrict__ vs, const float* __restrict__ cs,
                     const int* __restrict__ ic, float* __restrict__ e1) {
    int i = blockIdx.x;
    __shared__ float ai[384], sb1[384], sw2[384];
    int t = threadIdx.x;                 // 256 (4 waves)
    for (int k = t; k < 384; k += 256) {
        ai[k] = a[i * 384 + k]; sb1[k] = b1[k]; sw2[k] = w2[k];
    }
    __syncthreads();
    float b2v = b2[0];
    float cnt_i = (float)ic[i];
    int wave = t >> 6, lane = t & 63;
    for (int j = wave; j < 256; j += 4) {
        float s = 0.f;
        for (int k = lane; k < 384; k += 64) {
            float h = ai[k] - a[j * 384 + k] + sb1[k];
            if (h > 0.f) s += h * sw2[k];
        }
        #pragma unroll
        for (int off = 32; off > 0; off >>= 1) s += __shfl_down(s, off, 64);
        if (lane == 0) {
            float sw = 1.0f / (1.0f + expf(-(s + b2v)));
            float comb = 0.7f * vs[i * 256 + j] + 0.3f * cs[i * 256 + j];
            float cj = (float)ic[j];
            float mn = fminf(cnt_i, cj), mx = fmaxf(cnt_i, cj);
            float ratio = mn / fmaxf(mx, 1.0f);
            e1[i * 256 + j] = comb * sw * ratio;
        }
    }
}

// ---------------- K5: shared_sum/cnt, coalesced LDS-tiled (32x32 tiles) -----
__global__ void k_shared2(const int* __restrict__ co, const float* __restrict__ vs,
                          float* __restrict__ ss, float* __restrict__ sc) {
    int bi = blockIdx.x;                 // 0..63 (8x8 tiles)
    int i0 = (bi >> 3) * 32, j0 = (bi & 7) * 32;
    __shared__ float Mi[64][33], Ai[64][33], Mj[64][33], Aj[64][33];
    int t = threadIdx.x;                 // 256
    int tx = t & 15, ty = t >> 4;
    float s00=0.f,s01=0.f,s10=0.f,s11=0.f;
    float c00=0.f,c01=0.f,c10=0.f,c11=0.f;
    for (int k0 = 0; k0 < 256; k0 += 64) {
        #pragma unroll
        for (int s = 0; s < 8; s++) {
            int idx = s * 256 + t;
            int row = idx >> 6, kc = idx & 63;
            int ci = co[(i0 + row) * 256 + k0 + kc];
            float aa = ci > 50 ? 1.f : 0.f;
            Ai[kc][row] = aa;
            Mi[kc][row] = aa * vs[(i0 + row) * 256 + k0 + kc];
            int cj = co[(j0 + row) * 256 + k0 + kc];
            float ab = cj > 50 ? 1.f : 0.f;
            Aj[kc][row] = ab;
            Mj[kc][row] = ab * vs[(j0 + row) * 256 + k0 + kc];
        }
        __syncthreads();
        #pragma unroll 4
        for (int kk = 0; kk < 64; kk++) {
            float mi0 = Mi[kk][ty*2], mi1 = Mi[kk][ty*2+1];
            float ai0 = Ai[kk][ty*2], ai1 = Ai[kk][ty*2+1];
            float mj0 = Mj[kk][tx*2], mj1 = Mj[kk][tx*2+1];
            float aj0 = Aj[kk][tx*2], aj1 = Aj[kk][tx*2+1];
            s00 += mi0*mj0; s01 += mi0*mj1; s10 += mi1*mj0; s11 += mi1*mj1;
            c00 += ai0*aj0; c01 += ai0*aj1; c10 += ai1*aj0; c11 += ai1*aj1;
        }
        __syncthreads();
    }
    ss[(i0+ty*2)  *256 + j0+tx*2]   = s00; ss[(i0+ty*2)  *256 + j0+tx*2+1] = s01;
    ss[(i0+ty*2+1)*256 + j0+tx*2]   = s10; ss[(i0+ty*2+1)*256 + j0+tx*2+1] = s11;
    sc[(i0+ty*2)  *256 + j0+tx*2]   = c00; sc[(i0+ty*2)  *256 + j0+tx*2+1] = c01;
    sc[(i0+ty*2+1)*256 + j0+tx*2]   = c10; sc[(i0+ty*2+1)*256 + j0+tx*2+1] = c11;
}

// ---------------- K6: top-5, one wave per row (lowest-index tie-break) ------
__global__ void k_topk2(const int* __restrict__ co, float* __restrict__ topv,
                        int* __restrict__ topi) {
    int t = threadIdx.x;
    int lane = t & 63;
    int row = blockIdx.x * 4 + (t >> 6);
    int4 v4 = *(const int4*)(co + row * 256 + lane * 4);
    int key[4];
    key[0] = v4.x * 256 + (255 - (lane * 4 + 0));
    key[1] = v4.y * 256 + (255 - (lane * 4 + 1));
    key[2] = v4.z * 256 + (255 - (lane * 4 + 2));
    key[3] = v4.w * 256 + (255 - (lane * 4 + 3));
    for (int r = 0; r < 5; r++) {
        int best = key[0];
        #pragma unroll
        for (int e = 1; e < 4; e++) best = max(best, key[e]);
        #pragma unroll
        for (int off = 32; off > 0; off >>= 1) best = max(best, __shfl_xor(best, off, 64));
        int kidx = 255 - (best & 255);
        int val = best >> 8;
        if (lane == 0) { topv[row * 5 + r] = (float)val; topi[row * 5 + r] = kidx; }
        if ((kidx >> 2) == lane) key[kidx & 3] = -1;
    }
}

// ---------------- K7: assemble E (tiered), zero diag, per-row max -----------
__global__ void k_assemble(const int* __restrict__ co, const float* __restrict__ vs,
                           const float* __restrict__ cs, const float* __restrict__ e1,
                           const float* __restrict__ ss, const float* __restrict__ sc,
                           const float* __restrict__ topv, const int* __restrict__ topi,
                           float* __restrict__ E, float* __restrict__ partials) {
    int i = blockIdx.x, j = threadIdx.x;
    int cij = co[i * 256 + j];
    float e;
    if (i == j) {
        e = 0.f;
    } else if (cij > 50) {                 // tier1
        e = e1[i * 256 + j];
    } else if (cij > 10) {                 // tier2
        float conf = (float)cij / 50.0f;
        float comb = 0.7f * vs[i * 256 + j] + 0.3f * cs[i * 256 + j];
        float cnt = sc[i * 256 + j];
        float avg = ss[i * 256 + j] / fmaxf(cnt, 1.f);
        e = (cnt > 0.f) ? conf * comb + (1.f - conf) * avg : conf * comb;
    } else {                               // tier3: transitive via top-5
        float tvi[5], tvj[5]; int tii[5], tij[5];
        #pragma unroll
        for (int k = 0; k < 5; k++) {
            tvi[k] = topv[i * 5 + k]; tii[k] = topi[i * 5 + k];
            tvj[k] = topv[j * 5 + k]; tij[k] = topi[j * 5 + k];
        }
        float trans = 0.f, tot = 0.f;
        #pragma unroll
        for (int k = 0; k < 5; k++) {
            if (!(tvi[k] > 10.f)) continue;
            float vin_i = vs[i * 256 + tii[k]];
            #pragma unroll
            for (int l = 0; l < 5; l++) {
                if (!(tvj[l] > 10.f)) continue;
                int cc = co[tii[k] * 256 + tij[l]];
                if (cc <= 0) continue;
                float w = tvi[k] * tvj[l] / 50.f;
                float sim = vin_i * vs[j * 256 + tij[l]] * vs[tii[k] * 256 + tij[l]];
                trans += w * sim; tot += w;
            }
        }
        e = (tot > 0.f) ? trans / tot : 0.1f * cs[i * 256 + j];
    }
    E[i * 256 + j] = e;
    __shared__ float red[256];
    red[j] = e; __syncthreads();
    for (int off = 128; off > 0; off >>= 1) {
        if (j < off) red[j] = fmaxf(red[j], red[j + off]);
        __syncthreads();
    }
    if (j == 0) partials[i] = red[0];
}

// ---------------- K8: Ep = bf16(I + s*E), s = 1/max (fused scale) -----------
__global__ void k_ep(const float* __restrict__ E, const float* __restrict__ partials,
                     unsigned short* __restrict__ Ep) {
    __shared__ float red[256];
    int t = threadIdx.x;
    red[t] = partials[t]; __syncthreads();
    for (int off = 128; off > 0; off >>= 1) {
        if (t < off) red[t] = fmaxf(red[t], red[t + off]);
        __syncthreads();
    }
    float mx = red[0];
    float s = (mx > 0.f) ? 1.0f / mx : 1.0f;
    int base = (blockIdx.x * 256 + t) * 4;     // 64 blocks x 256 thr x 4 elems
    float4 e4 = *(const float4*)(E + base);
    float ev[4] = {e4.x, e4.y, e4.z, e4.w};
    unsigned short o[4];
    #pragma unroll
    for (int q = 0; q < 4; q++) {
        int g = base + q;
        float v = s * ev[q] + (((g >> 8) == (g & 255)) ? 1.0f : 0.0f);
        o[q] = f2bf(v);
    }
    uint2 w;
    w.x = (unsigned int)o[0] | ((unsigned int)o[1] << 16);
    w.y = (unsigned int)o[2] | ((unsigned int)o[3] << 16);
    *(uint2*)(Ep + base) = w;
}

// ---------------- K9: out[b,:,dtile] = Ep @ x[b,:,dtile]  (bf16 MFMA) -------
// Block: full i=256, d-tile=128, one batch. Ep fully resident in LDS.
// Ep LDS pitch 264 bf16 (528B, 16B-mult, bank-step 4 -> 2-way = free).
// xT LDS: [d][k] k-contiguous for B-frags, pitch 40 bf16 (80B).
#define PEP 264
#define PXT 40
__global__ __launch_bounds__(256, 1) void k_einsum_mfma(
    const unsigned short* __restrict__ Ep, const float* __restrict__ x,
    float* __restrict__ out) {
    extern __shared__ unsigned short smem[];
    unsigned short* eplds = smem;                 // 256*264*2 = 135168 B
    unsigned short* xt    = smem + 256 * PEP;     // 128*40*2  =  10240 B
    int t = threadIdx.x;
    int b = blockIdx.y;
    int d0 = blockIdx.x * 128;

    // ---- stage all of Ep into LDS (row-major, padded pitch) ----
    #pragma unroll
    for (int it = 0; it < 32; it++) {
        int c = it * 256 + t;                     // 16B chunk id (8 bf16)
        uint4 v = *(const uint4*)(Ep + (size_t)c * 8);
        *(uint4*)&eplds[(c >> 5) * PEP + (c & 31) * 8] = v;
    }

    // x staging mapping: thread covers d-col (t&127), k pairs
    int dcol = t & 127;
    int kp = (t >> 7) * 2;                        // 0 or 2
    const float* xb = x + ((size_t)b * 256) * 768 + d0 + dcol;

    int lane = t & 63;
    int lq = lane >> 4, l15 = lane & 15;
    int i0w = (t >> 6) * 64;                      // wave's i-range base

    f32x4 acc[4][8];
    #pragma unroll
    for (int gm = 0; gm < 4; gm++)
        #pragma unroll
        for (int gn = 0; gn < 8; gn++)
            #pragma unroll
            for (int e = 0; e < 4; e++) acc[gm][gn][e] = 0.f;

    float r0[8], r1[8];
    #pragma unroll
    for (int s = 0; s < 8; s++) {                 // prefetch k-tile 0
        int k = kp + 4 * s;
        r0[s] = xb[k * 768];
        r1[s] = xb[(k + 1) * 768];
    }

    for (int kt = 0; kt < 8; kt++) {              // 8 k-tiles of 32
        #pragma unroll
        for (int s = 0; s < 8; s++) {             // cvt+pack -> LDS (transposed)
            int k = kp + 4 * s;
            *(unsigned int*)&xt[dcol * PXT + k] = pack2bf(r0[s], r1[s]);
        }
        __syncthreads();
        if (kt < 7) {                             // prefetch next tile
            const float* xn = xb + (kt + 1) * 32 * 768;
            #pragma unroll
            for (int s = 0; s < 8; s++) {
                int k = kp + 4 * s;
                r0[s] = xn[k * 768];
                r1[s] = xn[(k + 1) * 768];
            }
        }
        int kg = kt * 32 + lq * 8;                // A-frag k offset (global k)
        bf16x8 av[4], bv[8];
        #pragma unroll
        for (int g = 0; g < 4; g++)
            av[g] = *(const bf16x8*)&eplds[(i0w + g * 16 + l15) * PEP + kg];
        #pragma unroll
        for (int g = 0; g < 8; g++)
            bv[g] = *(const bf16x8*)&xt[(g * 16 + l15) * PXT + lq * 8];
        #pragma unroll
        for (int gm = 0; gm < 4; gm++)
            #pragma unroll
            for (int gn = 0; gn < 8; gn++)
                acc[gm][gn] = __builtin_amdgcn_mfma_f32_16x16x32_bf16(
                    av[gm], bv[gn], acc[gm][gn], 0, 0, 0);
        __syncthreads();
    }

    // ---- epilogue: C/D layout col=lane&15, row=(lane>>4)*4+reg ----
    float* ob = out + ((size_t)b * 256) * 768 + d0;
    #pragma unroll
    for (int gm = 0; gm < 4; gm++) {
        #pragma unroll
        for (int gn = 0; gn < 8; gn++) {
            #pragma unroll
            for (int r = 0; r < 4; r++) {
                int i = i0w + gm * 16 + lq * 4 + r;
                int d = gn * 16 + l15;
                ob[(size_t)i * 768 + d] = acc[gm][gn][r];
            }
        }
    }
}

extern "C" void kernel_launch(void* const* d_in, const int* in_sizes, int n_in,
                              void* d_out, int out_size, void* d_ws, size_t ws_size,
                              hipStream_t stream) {
    const float* x   = (const float*)d_in[0];
    const float* cf  = (const float*)d_in[1];
    const float* ctx = (const float*)d_in[2];
    const float* w1  = (const float*)d_in[3];
    const float* b1  = (const float*)d_in[4];
    const float* w2  = (const float*)d_in[5];
    const float* b2  = (const float*)d_in[6];
    const int*   co  = (const int*)d_in[7];
    const int*   ic  = (const int*)d_in[8];
    float* out = (float*)d_out;

    float* ws   = (float*)d_ws;
    float* vsn  = ws;                        // 196608
    float* csn  = vsn + 196608;              // 196608
    float* a    = csn + 196608;              // 98304
    float* vs   = a + 98304;                 // 65536
    float* cs   = vs + 65536;                // 65536
    float* e1   = cs + 65536;                // 65536
    float* ss   = e1 + 65536;                // 65536
    float* sc   = ss + 65536;                // 65536
    float* E    = sc + 65536;                // 65536
    float* topv = E + 65536;                 // 1280
    int*   topi = (int*)(topv + 1280);       // 1280
    float* partials = (float*)(topi + 1280); // 256
    unsigned short* Ep = (unsigned short*)(partials + 256);  // 65536 bf16

    k_norm<<<512, 256, 0, stream>>>(cf, ctx, vsn, csn);
    k_a<<<32, 384, 0, stream>>>(cf, w1, a);
    k_gram2<<<128, 256, 0, stream>>>(vsn, csn, vs, cs);
    k_e1<<<256, 256, 0, stream>>>(a, b1, w2, b2, vs, cs, ic, e1);
    k_shared2<<<64, 256, 0, stream>>>(co, vs, ss, sc);
    k_topk2<<<64, 256, 0, stream>>>(co, topv, topi);
    k_assemble<<<256, 256, 0, stream>>>(co, vs, cs, e1, ss, sc, topv, topi, E, partials);
    k_ep<<<64, 256, 0, stream>>>(E, partials, Ep);
    size_t lds_bytes = (size_t)(256 * PEP + 128 * PXT) * sizeof(unsigned short); // 145408
    k_einsum_mfma<<<dim3(6, BATCH), 256, lds_bytes, stream>>>(Ep, x, out);
}

// Round 3
// 288.021 us; speedup vs baseline: 2.8904x; 1.6107x over previous
//
#include <hip/hip_runtime.h>
#include <hip/hip_bf16.h>
#include <math.h>

#define N 256
#define D 768
#define BATCH 128

typedef float f32x4 __attribute__((ext_vector_type(4)));
typedef short bf16x8 __attribute__((ext_vector_type(8)));

// RNE fp32 -> bf16 (no NaN inputs in this problem)
static __device__ __forceinline__ unsigned short f2bf(float f) {
    unsigned int u = __float_as_uint(f);
    u += 0x7fffu + ((u >> 16) & 1u);
    return (unsigned short)(u >> 16);
}
static __device__ __forceinline__ unsigned int pack2bf(float lo, float hi) {
    unsigned int a = __float_as_uint(lo);
    unsigned int b = __float_as_uint(hi);
    a += 0x7fffu + ((a >> 16) & 1u);
    b += 0x7fffu + ((b >> 16) & 1u);
    return (a >> 16) | (b & 0xffff0000u);
}

// ---------------- K1: row-normalize class & context features ----------------
__global__ void k_norm(const float* __restrict__ cf, const float* __restrict__ ctx,
                       float* __restrict__ vsn, float* __restrict__ csn) {
    int row = blockIdx.x;               // 0..511
    const float* src;
    float* dst;
    if (row < N) { src = cf  + row * D;       dst = vsn + row * D; }
    else         { src = ctx + (row - N) * D; dst = csn + (row - N) * D; }
    int t = threadIdx.x;                 // 256
    float s = 0.f;
    for (int d = t; d < D; d += 256) { float v = src[d]; s += v * v; }
    __shared__ float red[256];
    red[t] = s; __syncthreads();
    for (int off = 128; off > 0; off >>= 1) {
        if (t < off) red[t] += red[t + off];
        __syncthreads();
    }
    float inv = 1.0f / sqrtf(red[0]);
    for (int d = t; d < D; d += 256) dst[d] = src[d] * inv;
}

// ---------------- K2: a = cf @ w1, 32x32 tiles (256x384, K=768) -------------
__global__ void k_a2(const float* __restrict__ cf, const float* __restrict__ w1,
                     float* __restrict__ a) {
    int bi = blockIdx.x;                 // 96 blocks: 8 i-tiles x 12 j-tiles
    int i0 = (bi / 12) * 32, j0 = (bi % 12) * 32;
    __shared__ float Ci[64][33], Wj[64][33];   // [k][row/col], padded
    int t = threadIdx.x;                 // 256
    int tx = t & 15, ty = t >> 4;
    float a00 = 0.f, a01 = 0.f, a10 = 0.f, a11 = 0.f;
    for (int k0 = 0; k0 < 768; k0 += 64) {
        #pragma unroll
        for (int s = 0; s < 8; s++) {
            int idx = s * 256 + t;
            int row = idx >> 6, kc = idx & 63;       // cf: 32 rows x 64 k
            Ci[kc][row] = cf[(i0 + row) * 768 + k0 + kc];
            int kr = idx >> 5, col = idx & 31;       // w1: 64 k x 32 cols (k-major)
            Wj[kr][col] = w1[(k0 + kr) * 384 + j0 + col];
        }
        __syncthreads();
        #pragma unroll 4
        for (int kk = 0; kk < 64; kk++) {
            float iv0 = Ci[kk][ty * 2], iv1 = Ci[kk][ty * 2 + 1];
            float jv0 = Wj[kk][tx * 2], jv1 = Wj[kk][tx * 2 + 1];
            a00 += iv0 * jv0; a01 += iv0 * jv1;
            a10 += iv1 * jv0; a11 += iv1 * jv1;
        }
        __syncthreads();
    }
    a[(i0 + ty * 2)     * 384 + j0 + tx * 2]     = a00;
    a[(i0 + ty * 2)     * 384 + j0 + tx * 2 + 1] = a01;
    a[(i0 + ty * 2 + 1) * 384 + j0 + tx * 2]     = a10;
    a[(i0 + ty * 2 + 1) * 384 + j0 + tx * 2 + 1] = a11;
}

// ---------------- K3: vs/cs gram, coalesced LDS-tiled (32x32 tiles) ---------
__global__ void k_gram2(const float* __restrict__ vsn, const float* __restrict__ csn,
                        float* __restrict__ vs, float* __restrict__ cs) {
    int bx = blockIdx.x;                 // 0..127
    const float* S = (bx >= 64) ? csn : vsn;
    float* O       = (bx >= 64) ? cs  : vs;
    int bi = bx & 63;
    int i0 = (bi >> 3) * 32, j0 = (bi & 7) * 32;
    __shared__ float Li[64][33], Lj[64][33];   // [k][row], padded
    int t = threadIdx.x;                 // 256
    int tx = t & 15, ty = t >> 4;
    float a00 = 0.f, a01 = 0.f, a10 = 0.f, a11 = 0.f;
    for (int k0 = 0; k0 < 768; k0 += 64) {
        #pragma unroll
        for (int s = 0; s < 8; s++) {
            int idx = s * 256 + t;
            int row = idx >> 6, kc = idx & 63;
            Li[kc][row] = S[(i0 + row) * 768 + k0 + kc];
            Lj[kc][row] = S[(j0 + row) * 768 + k0 + kc];
        }
        __syncthreads();
        #pragma unroll 4
        for (int kk = 0; kk < 64; kk++) {
            float iv0 = Li[kk][ty * 2], iv1 = Li[kk][ty * 2 + 1];
            float jv0 = Lj[kk][tx * 2], jv1 = Lj[kk][tx * 2 + 1];
            a00 += iv0 * jv0; a01 += iv0 * jv1;
            a10 += iv1 * jv0; a11 += iv1 * jv1;
        }
        __syncthreads();
    }
    O[(i0 + ty * 2)     * 256 + j0 + tx * 2]     = a00;
    O[(i0 + ty * 2)     * 256 + j0 + tx * 2 + 1] = a01;
    O[(i0 + ty * 2 + 1) * 256 + j0 + tx * 2]     = a10;
    O[(i0 + ty * 2 + 1) * 256 + j0 + tx * 2 + 1] = a11;
}

// ---------------- K4: e1 pair-tiled: 16x16 (i,j) per block ------------------
// h = relu(ai - aj + b1); e1 = comb * sigmoid(h@w2 + b2) * ratio
// Stage ajm = aj - b1 so inner loop is fmaxf(ai - ajm, 0) * w2.
__global__ __launch_bounds__(256) void k_e1t(
    const float* __restrict__ a, const float* __restrict__ b1,
    const float* __restrict__ w2, const float* __restrict__ b2,
    const float* __restrict__ vs, const float* __restrict__ cs,
    const int* __restrict__ ic, float* __restrict__ e1) {
    int i0 = (blockIdx.x >> 4) * 16, j0 = (blockIdx.x & 15) * 16;
    __shared__ float ai[16][388], ajm[16][388];   // pitch 388 (%32 == 4)
    __shared__ float sw2[384];
    int t = threadIdx.x;                 // 256
    for (int idx = t; idx < 16 * 96; idx += 256) {
        int r = idx / 96, c = (idx % 96) * 4;
        *(float4*)&ai[r][c] = *(const float4*)(a + (i0 + r) * 384 + c);
        float4 u  = *(const float4*)(a + (j0 + r) * 384 + c);
        float4 bb = *(const float4*)(b1 + c);
        u.x -= bb.x; u.y -= bb.y; u.z -= bb.z; u.w -= bb.w;
        *(float4*)&ajm[r][c] = u;
    }
    for (int k = t; k < 384; k += 256) sw2[k] = w2[k];
    __syncthreads();
    int tx = t & 15, ty = t >> 4;
    float s = 0.f;
    #pragma unroll 4
    for (int k4 = 0; k4 < 96; k4++) {
        float4 xv = *(const float4*)&ai[ty][k4 * 4];
        float4 yv = *(const float4*)&ajm[tx][k4 * 4];
        float4 wv = *(const float4*)&sw2[k4 * 4];
        s += fmaxf(xv.x - yv.x, 0.f) * wv.x;
        s += fmaxf(xv.y - yv.y, 0.f) * wv.y;
        s += fmaxf(xv.z - yv.z, 0.f) * wv.z;
        s += fmaxf(xv.w - yv.w, 0.f) * wv.w;
    }
    int i = i0 + ty, j = j0 + tx;
    float sig = 1.0f / (1.0f + expf(-(s + b2[0])));
    float comb = 0.7f * vs[i * 256 + j] + 0.3f * cs[i * 256 + j];
    float ci = (float)ic[i], cj = (float)ic[j];
    float mn = fminf(ci, cj), mx = fmaxf(ci, cj);
    float ratio = mn / fmaxf(mx, 1.0f);
    e1[i * 256 + j] = comb * sig * ratio;
}

// ---------------- K5: shared_sum/cnt, coalesced LDS-tiled (32x32 tiles) -----
__global__ void k_shared2(const int* __restrict__ co, const float* __restrict__ vs,
                          float* __restrict__ ss, float* __restrict__ sc) {
    int bi = blockIdx.x;                 // 0..63 (8x8 tiles)
    int i0 = (bi >> 3) * 32, j0 = (bi & 7) * 32;
    __shared__ float Mi[64][33], Ai[64][33], Mj[64][33], Aj[64][33];
    int t = threadIdx.x;                 // 256
    int tx = t & 15, ty = t >> 4;
    float s00=0.f,s01=0.f,s10=0.f,s11=0.f;
    float c00=0.f,c01=0.f,c10=0.f,c11=0.f;
    for (int k0 = 0; k0 < 256; k0 += 64) {
        #pragma unroll
        for (int s = 0; s < 8; s++) {
            int idx = s * 256 + t;
            int row = idx >> 6, kc = idx & 63;
            int ci = co[(i0 + row) * 256 + k0 + kc];
            float aa = ci > 50 ? 1.f : 0.f;
            Ai[kc][row] = aa;
            Mi[kc][row] = aa * vs[(i0 + row) * 256 + k0 + kc];
            int cj = co[(j0 + row) * 256 + k0 + kc];
            float ab = cj > 50 ? 1.f : 0.f;
            Aj[kc][row] = ab;
            Mj[kc][row] = ab * vs[(j0 + row) * 256 + k0 + kc];
        }
        __syncthreads();
        #pragma unroll 4
        for (int kk = 0; kk < 64; kk++) {
            float mi0 = Mi[kk][ty*2], mi1 = Mi[kk][ty*2+1];
            float ai0 = Ai[kk][ty*2], ai1 = Ai[kk][ty*2+1];
            float mj0 = Mj[kk][tx*2], mj1 = Mj[kk][tx*2+1];
            float aj0 = Aj[kk][tx*2], aj1 = Aj[kk][tx*2+1];
            s00 += mi0*mj0; s01 += mi0*mj1; s10 += mi1*mj0; s11 += mi1*mj1;
            c00 += ai0*aj0; c01 += ai0*aj1; c10 += ai1*aj0; c11 += ai1*aj1;
        }
        __syncthreads();
    }
    ss[(i0+ty*2)  *256 + j0+tx*2]   = s00; ss[(i0+ty*2)  *256 + j0+tx*2+1] = s01;
    ss[(i0+ty*2+1)*256 + j0+tx*2]   = s10; ss[(i0+ty*2+1)*256 + j0+tx*2+1] = s11;
    sc[(i0+ty*2)  *256 + j0+tx*2]   = c00; sc[(i0+ty*2)  *256 + j0+tx*2+1] = c01;
    sc[(i0+ty*2+1)*256 + j0+tx*2]   = c10; sc[(i0+ty*2+1)*256 + j0+tx*2+1] = c11;
}

// ---------------- K6: top-5, one wave per row (lowest-index tie-break) ------
__global__ void k_topk2(const int* __restrict__ co, float* __restrict__ topv,
                        int* __restrict__ topi) {
    int t = threadIdx.x;
    int lane = t & 63;
    int row = blockIdx.x * 4 + (t >> 6);
    int4 v4 = *(const int4*)(co + row * 256 + lane * 4);
    int key[4];
    key[0] = v4.x * 256 + (255 - (lane * 4 + 0));
    key[1] = v4.y * 256 + (255 - (lane * 4 + 1));
    key[2] = v4.z * 256 + (255 - (lane * 4 + 2));
    key[3] = v4.w * 256 + (255 - (lane * 4 + 3));
    for (int r = 0; r < 5; r++) {
        int best = key[0];
        #pragma unroll
        for (int e = 1; e < 4; e++) best = max(best, key[e]);
        #pragma unroll
        for (int off = 32; off > 0; off >>= 1) best = max(best, __shfl_xor(best, off, 64));
        int kidx = 255 - (best & 255);
        int val = best >> 8;
        if (lane == 0) { topv[row * 5 + r] = (float)val; topi[row * 5 + r] = kidx; }
        if ((kidx >> 2) == lane) key[kidx & 3] = -1;
    }
}

// ---------------- K7: assemble E (tiered), zero diag, per-row max -----------
__global__ void k_assemble(const int* __restrict__ co, const float* __restrict__ vs,
                           const float* __restrict__ cs, const float* __restrict__ e1,
                           const float* __restrict__ ss, const float* __restrict__ sc,
                           const float* __restrict__ topv, const int* __restrict__ topi,
                           float* __restrict__ E, float* __restrict__ partials) {
    int i = blockIdx.x, j = threadIdx.x;
    int cij = co[i * 256 + j];
    float e;
    if (i == j) {
        e = 0.f;
    } else if (cij > 50) {                 // tier1
        e = e1[i * 256 + j];
    } else if (cij > 10) {                 // tier2
        float conf = (float)cij / 50.0f;
        float comb = 0.7f * vs[i * 256 + j] + 0.3f * cs[i * 256 + j];
        float cnt = sc[i * 256 + j];
        float avg = ss[i * 256 + j] / fmaxf(cnt, 1.f);
        e = (cnt > 0.f) ? conf * comb + (1.f - conf) * avg : conf * comb;
    } else {                               // tier3: transitive via top-5
        float tvi[5], tvj[5]; int tii[5], tij[5];
        #pragma unroll
        for (int k = 0; k < 5; k++) {
            tvi[k] = topv[i * 5 + k]; tii[k] = topi[i * 5 + k];
            tvj[k] = topv[j * 5 + k]; tij[k] = topi[j * 5 + k];
        }
        float trans = 0.f, tot = 0.f;
        #pragma unroll
        for (int k = 0; k < 5; k++) {
            if (!(tvi[k] > 10.f)) continue;
            float vin_i = vs[i * 256 + tii[k]];
            #pragma unroll
            for (int l = 0; l < 5; l++) {
                if (!(tvj[l] > 10.f)) continue;
                int cc = co[tii[k] * 256 + tij[l]];
                if (cc <= 0) continue;
                float w = tvi[k] * tvj[l] / 50.f;
                float sim = vin_i * vs[j * 256 + tij[l]] * vs[tii[k] * 256 + tij[l]];
                trans += w * sim; tot += w;
            }
        }
        e = (tot > 0.f) ? trans / tot : 0.1f * cs[i * 256 + j];
    }
    E[i * 256 + j] = e;
    __shared__ float red[256];
    red[j] = e; __syncthreads();
    for (int off = 128; off > 0; off >>= 1) {
        if (j < off) red[j] = fmaxf(red[j], red[j + off]);
        __syncthreads();
    }
    if (j == 0) partials[i] = red[0];
}

// ---------------- K8: Ep = bf16(I + s*E), s = 1/max (fused scale) -----------
__global__ void k_ep(const float* __restrict__ E, const float* __restrict__ partials,
                     unsigned short* __restrict__ Ep) {
    __shared__ float red[256];
    int t = threadIdx.x;
    red[t] = partials[t]; __syncthreads();
    for (int off = 128; off > 0; off >>= 1) {
        if (t < off) red[t] = fmaxf(red[t], red[t + off]);
        __syncthreads();
    }
    float mx = red[0];
    float s = (mx > 0.f) ? 1.0f / mx : 1.0f;
    int base = (blockIdx.x * 256 + t) * 4;     // 64 blocks x 256 thr x 4 elems
    float4 e4 = *(const float4*)(E + base);
    float ev[4] = {e4.x, e4.y, e4.z, e4.w};
    unsigned short o[4];
    #pragma unroll
    for (int q = 0; q < 4; q++) {
        int g = base + q;
        float v = s * ev[q] + (((g >> 8) == (g & 255)) ? 1.0f : 0.0f);
        o[q] = f2bf(v);
    }
    uint2 w;
    w.x = (unsigned int)o[0] | ((unsigned int)o[1] << 16);
    w.y = (unsigned int)o[2] | ((unsigned int)o[3] << 16);
    *(uint2*)(Ep + base) = w;
}

// ---------------- K9: out[b,:,dtile] = Ep @ x[b,:,dtile]  (bf16 MFMA) -------
// Block: full i=256, d-tile=128, one batch. Ep fully resident in LDS.
// Ep LDS pitch 264 bf16 (528B, 16B-mult, bank-step 4 -> 2-way = free).
// xT LDS: [d][k] k-contiguous for B-frags, pitch 40 bf16 (80B).
#define PEP 264
#define PXT 40
__global__ __launch_bounds__(256, 1) void k_einsum_mfma(
    const unsigned short* __restrict__ Ep, const float* __restrict__ x,
    float* __restrict__ out) {
    extern __shared__ unsigned short smem[];
    unsigned short* eplds = smem;                 // 256*264*2 = 135168 B
    unsigned short* xt    = smem + 256 * PEP;     // 128*40*2  =  10240 B
    int t = threadIdx.x;
    int b = blockIdx.y;
    int d0 = blockIdx.x * 128;

    // ---- stage all of Ep into LDS (row-major, padded pitch) ----
    #pragma unroll
    for (int it = 0; it < 32; it++) {
        int c = it * 256 + t;                     // 16B chunk id (8 bf16)
        uint4 v = *(const uint4*)(Ep + (size_t)c * 8);
        *(uint4*)&eplds[(c >> 5) * PEP + (c & 31) * 8] = v;
    }

    // x staging mapping: thread covers d-col (t&127), k pairs
    int dcol = t & 127;
    int kp = (t >> 7) * 2;                        // 0 or 2
    const float* xb = x + ((size_t)b * 256) * 768 + d0 + dcol;

    int lane = t & 63;
    int lq = lane >> 4, l15 = lane & 15;
    int i0w = (t >> 6) * 64;                      // wave's i-range base

    f32x4 acc[4][8];
    #pragma unroll
    for (int gm = 0; gm < 4; gm++)
        #pragma unroll
        for (int gn = 0; gn < 8; gn++)
            #pragma unroll
            for (int e = 0; e < 4; e++) acc[gm][gn][e] = 0.f;

    float r0[8], r1[8];
    #pragma unroll
    for (int s = 0; s < 8; s++) {                 // prefetch k-tile 0
        int k = kp + 4 * s;
        r0[s] = xb[k * 768];
        r1[s] = xb[(k + 1) * 768];
    }

    for (int kt = 0; kt < 8; kt++) {              // 8 k-tiles of 32
        #pragma unroll
        for (int s = 0; s < 8; s++) {             // cvt+pack -> LDS (transposed)
            int k = kp + 4 * s;
            *(unsigned int*)&xt[dcol * PXT + k] = pack2bf(r0[s], r1[s]);
        }
        __syncthreads();
        if (kt < 7) {                             // prefetch next tile
            const float* xn = xb + (kt + 1) * 32 * 768;
            #pragma unroll
            for (int s = 0; s < 8; s++) {
                int k = kp + 4 * s;
                r0[s] = xn[k * 768];
                r1[s] = xn[(k + 1) * 768];
            }
        }
        int kg = kt * 32 + lq * 8;                // A-frag k offset (global k)
        bf16x8 av[4], bv[8];
        #pragma unroll
        for (int g = 0; g < 4; g++)
            av[g] = *(const bf16x8*)&eplds[(i0w + g * 16 + l15) * PEP + kg];
        #pragma unroll
        for (int g = 0; g < 8; g++)
            bv[g] = *(const bf16x8*)&xt[(g * 16 + l15) * PXT + lq * 8];
        #pragma unroll
        for (int gm = 0; gm < 4; gm++)
            #pragma unroll
            for (int gn = 0; gn < 8; gn++)
                acc[gm][gn] = __builtin_amdgcn_mfma_f32_16x16x32_bf16(
                    av[gm], bv[gn], acc[gm][gn], 0, 0, 0);
        __syncthreads();
    }

    // ---- epilogue: C/D layout col=lane&15, row=(lane>>4)*4+reg ----
    float* ob = out + ((size_t)b * 256) * 768 + d0;
    #pragma unroll
    for (int gm = 0; gm < 4; gm++) {
        #pragma unroll
        for (int gn = 0; gn < 8; gn++) {
            #pragma unroll
            for (int r = 0; r < 4; r++) {
                int i = i0w + gm * 16 + lq * 4 + r;
                int d = gn * 16 + l15;
                ob[(size_t)i * 768 + d] = acc[gm][gn][r];
            }
        }
    }
}

extern "C" void kernel_launch(void* const* d_in, const int* in_sizes, int n_in,
                              void* d_out, int out_size, void* d_ws, size_t ws_size,
                              hipStream_t stream) {
    const float* x   = (const float*)d_in[0];
    const float* cf  = (const float*)d_in[1];
    const float* ctx = (const float*)d_in[2];
    const float* w1  = (const float*)d_in[3];
    const float* b1  = (const float*)d_in[4];
    const float* w2  = (const float*)d_in[5];
    const float* b2  = (const float*)d_in[6];
    const int*   co  = (const int*)d_in[7];
    const int*   ic  = (const int*)d_in[8];
    float* out = (float*)d_out;

    float* ws   = (float*)d_ws;
    float* vsn  = ws;                        // 196608
    float* csn  = vsn + 196608;              // 196608
    float* a    = csn + 196608;              // 98304
    float* vs   = a + 98304;                 // 65536
    float* cs   = vs + 65536;                // 65536
    float* e1   = cs + 65536;                // 65536
    float* ss   = e1 + 65536;                // 65536
    float* sc   = ss + 65536;                // 65536
    float* E    = sc + 65536;                // 65536
    float* topv = E + 65536;                 // 1280
    int*   topi = (int*)(topv + 1280);       // 1280
    float* partials = (float*)(topi + 1280); // 256
    unsigned short* Ep = (unsigned short*)(partials + 256);  // 65536 bf16

    k_norm<<<512, 256, 0, stream>>>(cf, ctx, vsn, csn);
    k_a2<<<96, 256, 0, stream>>>(cf, w1, a);
    k_gram2<<<128, 256, 0, stream>>>(vsn, csn, vs, cs);
    k_e1t<<<256, 256, 0, stream>>>(a, b1, w2, b2, vs, cs, ic, e1);
    k_shared2<<<64, 256, 0, stream>>>(co, vs, ss, sc);
    k_topk2<<<64, 256, 0, stream>>>(co, topv, topi);
    k_assemble<<<256, 256, 0, stream>>>(co, vs, cs, e1, ss, sc, topv, topi, E, partials);
    k_ep<<<64, 256, 0, stream>>>(E, partials, Ep);
    size_t lds_bytes = (size_t)(256 * PEP + 128 * PXT) * sizeof(unsigned short); // 145408
    k_einsum_mfma<<<dim3(6, BATCH), 256, lds_bytes, stream>>>(Ep, x, out);
}